// Round 1
// baseline (303.879 us; speedup 1.0000x reference)
//
#include <hip/hip_runtime.h>
#include <math.h>

// SPP: out = concat(x, mp5(x), mp9(x), mp13(x)) along channels.
// x: (32, 512, 32, 32) fp32  ->  out: (32, 2048, 32, 32) fp32.
// Key identities: mp9 = mp5(mp5(x)), mp13 = mp5(mp9(x)) for stride-1,
// -inf-padded max pools; each mp5 is separable (row max5, then col max5).
// One block per (n,c) plane; plane lives in LDS; 3 successive mp5 stages.

constexpr int W = 32;
constexpr int H = 32;
constexpr int HWSZ = 1024;       // 32*32
constexpr int STR = 36;          // LDS row stride: keeps float4 16B-aligned
                                 // (c0 % 4 == 0 -> 36r+c0 % 4 == 0) and
                                 // spreads the 8 rows of a wave across banks
constexpr int C_IN = 512;
constexpr int C_OUT = 2048;

__global__ __launch_bounds__(256) void spp_kernel(const float* __restrict__ x,
                                                  float* __restrict__ out) {
    __shared__ float A[H * STR];
    __shared__ float B[H * STR];

    const int plane = blockIdx.x;          // n*512 + c
    const int n = plane >> 9;
    const int c = plane & 511;
    const int t = threadIdx.x;
    const int e0 = t << 2;                 // this thread's 4 consecutive elems
    const int r  = e0 >> 5;                // row (fixed: 4 elems within a row)
    const int c0 = e0 & 31;                // col start, multiple of 4

    const float* src = x + (size_t)plane * HWSZ;
    const size_t obase = (size_t)n * C_OUT * HWSZ + (size_t)c * HWSZ;

    // Load plane (coalesced float4), emit the identity chunk, stage to LDS.
    float4 v = *(const float4*)(src + e0);
    *(float4*)(out + obase + e0) = v;
    *(float4*)(&A[r * STR + c0]) = v;
    __syncthreads();

    #pragma unroll
    for (int p = 0; p < 3; ++p) {
        // ---- row pass: B[r][c] = max(A[r][c-2 .. c+2]), clipped ----
        float win[8];
        #pragma unroll
        for (int i = 0; i < 8; ++i) {
            const int cc = c0 - 2 + i;
            win[i] = (cc >= 0 && cc < W) ? A[r * STR + cc] : -INFINITY;
        }
        float4 rm;
        rm.x = fmaxf(fmaxf(fmaxf(win[0], win[1]), fmaxf(win[2], win[3])), win[4]);
        rm.y = fmaxf(fmaxf(fmaxf(win[1], win[2]), fmaxf(win[3], win[4])), win[5]);
        rm.z = fmaxf(fmaxf(fmaxf(win[2], win[3]), fmaxf(win[4], win[5])), win[6]);
        rm.w = fmaxf(fmaxf(fmaxf(win[3], win[4]), fmaxf(win[5], win[6])), win[7]);
        *(float4*)(&B[r * STR + c0]) = rm;
        __syncthreads();   // B fully written before col pass reads it

        // ---- col pass: m[c] = max(B[r-2 .. r+2][c]), clipped ----
        float4 m = make_float4(-INFINITY, -INFINITY, -INFINITY, -INFINITY);
        #pragma unroll
        for (int dr = -2; dr <= 2; ++dr) {
            const int rr = r + dr;
            if (rr >= 0 && rr < H) {
                float4 b = *(const float4*)(&B[rr * STR + c0]);
                m.x = fmaxf(m.x, b.x);
                m.y = fmaxf(m.y, b.y);
                m.z = fmaxf(m.z, b.z);
                m.w = fmaxf(m.w, b.w);
            }
        }

        // Emit this pyramid level: channel block (p+1)*512.
        *(float4*)(out + obase + (size_t)(p + 1) * C_IN * HWSZ + e0) = m;

        // Feed result back into A for the next stage.
        __syncthreads();   // all col-pass reads of B done; A reads long done
        *(float4*)(&A[r * STR + c0]) = m;
        __syncthreads();   // A fully written before next row pass
    }
}

extern "C" void kernel_launch(void* const* d_in, const int* in_sizes, int n_in,
                              void* d_out, int out_size, void* d_ws, size_t ws_size,
                              hipStream_t stream) {
    const float* x = (const float*)d_in[0];
    float* out = (float*)d_out;
    const int planes = 32 * 512;   // one block per (n, c) plane
    spp_kernel<<<planes, 256, 0, stream>>>(x, out);
}